// Round 13
// baseline (120.484 us; speedup 1.0000x reference)
//
#include <hip/hip_runtime.h>

// BatchIndependentLoss: SupCon-style loss, B=2048, V=2, D=256, N=4096.
// loss = -mean_i( lp_i - (W_i - e^{lp}*lp) / u_new[i%B] )
// R13: PER-WAVE-TAX amortization. 12 rounds: gemm cost tracks TOTAL WAVE
// COUNT (4096 waves -> ~42us; 2080 waves -> ~29-31us) and is invariant to
// staging path / prefetch / block shape / epilogue / atomics / code size;
// per-wave lifetime ~70K cyc vs ~3K work. So: 2 tiles per wave
// (1040 waves = 260 blocks x 4), R8's validated per-tile body. Tile-1's
// exp epilogue overlaps tile-2's fragment loads within the wave (no
// barriers). sd==1 (unit-normalized feats; validated R10 absmax 0.0).
// Structure: memset(E,W2) + prep(pack only) + gemm(260x256) + finalize.
//
// CmF layout: shorts, index = ((band*8 + k)*4 + rt)*512 + (l15*4+quad)*8 + j
// Fragment load for (band, k, rt): wave reads one contiguous 1 KB chunk.

#define BSZ   2048
#define NROW  4096
#define NB64  64                       // 4096/64 bands
#define NT2   (NB64 * (NB64 + 1) / 2)  // 2080 upper-triangle 64x64 tiles
#define NWAVE (NT2 / 2)                // 1040 waves, 2 tiles each
#define C1    (1.4426950408889634f / 0.07f)   // log2(e)/TEMPERATURE
#define LN2   0.6931471805599453f

typedef __attribute__((ext_vector_type(8))) __bf16 bf16x8;
typedef __attribute__((ext_vector_type(4))) float f32x4;

__device__ __forceinline__ short f2bs(float x) {
    __bf16 b = (__bf16)x;
    return __builtin_bit_cast(short, b);
}

// contrast row i = v*B + b  ->  features row b*V + v  (fp32, 256 elems)
__device__ __forceinline__ const float* crow_ptr(const float* feats, int i) {
    return feats + (((i & (BSZ - 1)) * 2 + (i >> 11)) << 8);
}

// ---------------- prep: frag-major bf16 pack (validated R8 mapping) --------
__global__ __launch_bounds__(256) void prep_kernel(const float* __restrict__ feats,
        short* __restrict__ CmF) {
    int gid  = blockIdx.x * 256 + threadIdx.x;   // 0..262143
    int quad = gid & 3;
    int l15  = (gid >> 2) & 15;
    int rt   = (gid >> 6) & 3;
    int k    = (gid >> 8) & 7;
    int b    = gid >> 12;
    int srow = (b << 6) + (rt << 4) + l15;
    int kel  = (k << 5) + (quad << 3);
    const float4* fp = (const float4*)(crow_ptr(feats, srow) + kel);
    float4 v0 = fp[0], v1 = fp[1];
    short h[8] = { f2bs(v0.x), f2bs(v0.y), f2bs(v0.z), f2bs(v0.w),
                   f2bs(v1.x), f2bs(v1.y), f2bs(v1.z), f2bs(v1.w) };
    *(int4*)(CmF + gid * 8) = *(int4*)h;
}

// ---------------- per-tile body (R8-validated, sd==1 exp2 domain) ----------
__device__ __forceinline__ void do_tile(int t, int lane, int quad, int l15,
        const short* __restrict__ CmF, float* __restrict__ E,
        float* __restrict__ W2, float* __restrict__ Lpos) {
    // triangle decode t -> (p,q), p>=q
    int p = (int)((sqrtf(8.0f * (float)t + 1.0f) - 1.0f) * 0.5f);
    while ((p + 1) * (p + 2) / 2 <= t) ++p;
    while (p * (p + 1) / 2 > t) --p;
    int q = t - p * (p + 1) / 2;
    int rowBase = q << 6;
    int colBase = p << 6;
    bool offdiag = (p != q);

    const short* aB = CmF + q * 16384 + ((l15 << 2) + quad) * 8;
    const short* bB = CmF + p * 16384 + ((l15 << 2) + quad) * 8;

    f32x4 acc[4][4];
    #pragma unroll
    for (int a = 0; a < 4; ++a)
        #pragma unroll
        for (int c = 0; c < 4; ++c) acc[a][c] = (f32x4){0.f, 0.f, 0.f, 0.f};

    // depth-2 software pipeline: 3 rotating fragment buffers
    bf16x8 aF[3][4], bF[3][4];
    #pragma unroll
    for (int rt = 0; rt < 4; ++rt) {
        aF[0][rt] = *(const bf16x8*)(aB + (0 * 4 + rt) * 512);
        bF[0][rt] = *(const bf16x8*)(bB + (0 * 4 + rt) * 512);
    }
    #pragma unroll
    for (int rt = 0; rt < 4; ++rt) {
        aF[1][rt] = *(const bf16x8*)(aB + (1 * 4 + rt) * 512);
        bF[1][rt] = *(const bf16x8*)(bB + (1 * 4 + rt) * 512);
    }
    #pragma unroll
    for (int k = 0; k < 8; ++k) {
        int cur = k % 3;
        int nxt = (k + 2) % 3;
        if (k < 6) {
            #pragma unroll
            for (int rt = 0; rt < 4; ++rt) {
                aF[nxt][rt] = *(const bf16x8*)(aB + ((k + 2) * 4 + rt) * 512);
                bF[nxt][rt] = *(const bf16x8*)(bB + ((k + 2) * 4 + rt) * 512);
            }
        }
        #pragma unroll
        for (int rt = 0; rt < 4; ++rt)
            #pragma unroll
            for (int ct = 0; ct < 4; ++ct)
                acc[rt][ct] = __builtin_amdgcn_mfma_f32_16x16x32_bf16(
                    aF[cur][rt], bF[cur][ct], acc[rt][ct], 0, 0, 0);
    }

    // epilogue (sd==1): tt = d*C1 - C1; e = exp2(tt); col-view == row-view.
    // C/D layout: col = lane&15, row = quad*4 + reg  [m89/m91]
    float Ep[4][4] = {}, Wp[4][4] = {};
    float Ec[4] = {}, Wc[4] = {};
    #pragma unroll
    for (int rt = 0; rt < 4; ++rt) {
        #pragma unroll
        for (int ct = 0; ct < 4; ++ct) {
            #pragma unroll
            for (int r = 0; r < 4; ++r) {
                float d = acc[rt][ct][r];
                float tt = __builtin_fmaf(d, C1, -C1);
                float e = __builtin_exp2f(tt);
                Ep[rt][r] += e;
                Wp[rt][r] = __builtin_fmaf(e, tt, Wp[rt][r]);
                if (offdiag) {
                    Ec[ct] += e;
                    Wc[ct] = __builtin_fmaf(e, tt, Wc[ct]);
                }
            }
        }
    }

    // Lpos: tiles p==q^32 hold positives (j=i^2048) on the tile diagonal
    if (p == (q ^ 32)) {
        if (quad == (l15 >> 2)) {
            int r = l15 & 3;
            #pragma unroll
            for (int rt = 0; rt < 4; ++rt) {
                float lp = __builtin_fmaf(acc[rt][rt][r], C1, -C1);
                Lpos[rowBase + rt * 16 + l15] = lp;
                Lpos[colBase + rt * 16 + l15] = lp;
            }
        }
    }

    // row-path: reduce over 16 l15 lanes per row, 1-lane atomic per row
    #pragma unroll
    for (int rt = 0; rt < 4; ++rt) {
        #pragma unroll
        for (int r = 0; r < 4; ++r) {
            float e = Ep[rt][r], w = Wp[rt][r];
            #pragma unroll
            for (int off = 1; off < 16; off <<= 1) {
                e += __shfl_xor(e, off, 64);
                w += __shfl_xor(w, off, 64);
            }
            if (l15 == 0) {
                int grow = rowBase + rt * 16 + (quad << 2) + r;
                atomicAdd(&E[grow], e);
                atomicAdd(&W2[grow], w);
            }
        }
    }
    // col-path: reduce over 4 quads per col, 16-lane atomic
    if (offdiag) {
        #pragma unroll
        for (int ct = 0; ct < 4; ++ct) {
            float e = Ec[ct], w = Wc[ct];
            e += __shfl_xor(e, 16, 64);  w += __shfl_xor(w, 16, 64);
            e += __shfl_xor(e, 32, 64);  w += __shfl_xor(w, 32, 64);
            if (quad == 0) {
                int gcol = colBase + ct * 16 + l15;
                atomicAdd(&E[gcol], e);
                atomicAdd(&W2[gcol], w);
            }
        }
    }
}

// ---------------- gemm: 260 blocks x 4 waves, 2 tiles per wave -------------
__global__ __launch_bounds__(256, 2) void gemm_sym(const short* __restrict__ CmF,
        float* __restrict__ E, float* __restrict__ W2, float* __restrict__ Lpos) {
    int tid  = threadIdx.x;
    int wave = tid >> 6;
    int lane = tid & 63;
    int quad = lane >> 4;
    int l15  = lane & 15;
    int g = blockIdx.x * 4 + wave;       // 0..1039
    do_tile(g,         lane, quad, l15, CmF, E, W2, Lpos);
    do_tile(g + NWAVE, lane, quad, l15, CmF, E, W2, Lpos);
}

// ---------------- finalize: u_new + scalar reduction (exp2 domain) ---------
__global__ __launch_bounds__(1024) void finalize_kernel(const int* __restrict__ index,
        const float* __restrict__ u, const float* __restrict__ E,
        const float* __restrict__ W2, const float* __restrict__ Lpos,
        float* __restrict__ out) {
    __shared__ float unew[BSZ];
    __shared__ float partial[16];
    int tid = threadIdx.x;
    for (int b = tid; b < BSZ; b += 1024) {
        float tp = Lpos[b];
        unew[b] = 0.1f * u[index[b]] + 0.9f * (E[b] - __builtin_exp2f(tp));
    }
    __syncthreads();
    float local = 0.0f;
    for (int i = tid; i < NROW; i += 1024) {
        float tp  = Lpos[i];
        float etp = __builtin_exp2f(tp);
        local += tp - (W2[i] - etp * tp) / unew[i & (BSZ - 1)];
    }
    #pragma unroll
    for (int off = 32; off; off >>= 1) local += __shfl_xor(local, off, 64);
    if ((tid & 63) == 0) partial[tid >> 6] = local;
    __syncthreads();
    if (tid == 0) {
        float s = 0.0f;
        #pragma unroll
        for (int w = 0; w < 16; ++w) s += partial[w];
        out[0] = -LN2 * s / (float)NROW;   // exp2-domain -> nat-log domain
    }
}

extern "C" void kernel_launch(void* const* d_in, const int* in_sizes, int n_in,
                              void* d_out, int out_size, void* d_ws, size_t ws_size,
                              hipStream_t stream) {
    const int*   index = (const int*)d_in[0];
    const float* feats = (const float*)d_in[1];
    const float* u     = (const float*)d_in[2];
    float* out = (float*)d_out;

    // ws: [E | W2 | Lpos] (48 KB) | CmF @128KB (2 MB)
    float* E    = (float*)d_ws;
    float* W2   = E + NROW;
    float* Lpos = W2 + NROW;
    short* CmF  = (short*)((char*)d_ws + 131072);

    hipMemsetAsync(E, 0, 2 * NROW * sizeof(float), stream);   // zero E, W2
    prep_kernel<<<1024, 256, 0, stream>>>(feats, CmF);
    gemm_sym<<<260, 256, 0, stream>>>(CmF, E, W2, Lpos);
    finalize_kernel<<<1, 1024, 0, stream>>>(index, u, E, W2, Lpos, out);
}